// Round 4
// baseline (372.212 us; speedup 1.0000x reference)
//
#include <hip/hip_runtime.h>

// LaplacianRegularizer3D: 2 * sum over 13 forward shifts
//   S13 = {(1,0,0)} u {(dk,0,1)} u {(dk,1,dj)},  dk,dj in {-1,0,1}
// over x = f.reshape(8,12,8,256,256).
// Register-marching: one wave owns a strip of 4 consecutive rows of one
// (b,c) image, all 8 k-planes in registers. Per step it loads only row i+1
// (8 float4 loads), computes row i's within-row terms + (i,i+1) cross terms,
// then rolls nxt->cur. HBM traffic = 5/4 * 201 MB ~= 251 MB (vs 2x before).
// j-edges via shuffle (wave spans the whole 256-wide row as 64 x float4).

constexpr int WIDTH  = 256;
constexpr int HWs    = 256 * 256;
constexpr int NSTRIP = 8 * 12 * 256 / 4;   // 6144 strips
constexpr int NBLOCK = NSTRIP / 4;          // 1536 blocks (4 waves each)

__global__ __launch_bounds__(256, 4) void lap3d(const float* __restrict__ f,
                                                float* __restrict__ partial) {
    const int tid  = threadIdx.x;
    const int lane = tid & 63;
    const int wid  = tid >> 6;
    const int ss   = blockIdx.x * 4 + wid;   // strip id
    const int bc   = ss >> 6;                // 0..95
    const int i0   = (ss & 63) << 2;         // 0,4,...,252
    const float* base = f + (size_t)bc * 8 * HWs + (size_t)i0 * WIDTH + (size_t)lane * 4;

    const bool has_right  = (lane < 63);
    const bool has_left   = (lane > 0);
    const bool last_strip = (i0 == 252);     // wave-uniform

    float cur[8][4];
#pragma unroll
    for (int k = 0; k < 8; ++k) {
        float4 v = *reinterpret_cast<const float4*>(base + k * HWs);
        cur[k][0] = v.x; cur[k][1] = v.y; cur[k][2] = v.z; cur[k][3] = v.w;
    }

    float acc = 0.f;

#pragma unroll
    for (int s = 0; s < 4; ++s) {
        const bool hn = (s < 3) || !last_strip;   // wave-uniform branch
        float nxt[8][4];
        if (hn) {
            const float* nb = base + (s + 1) * WIDTH;
#pragma unroll
            for (int k = 0; k < 8; ++k) {
                float4 v = *reinterpret_cast<const float4*>(nb + k * HWs);
                nxt[k][0] = v.x; nxt[k][1] = v.y; nxt[k][2] = v.z; nxt[k][3] = v.w;
            }
        }

        // ---- within-row terms on cur ----
        // s = (1,0,0)
#pragma unroll
        for (int k = 0; k < 7; ++k)
#pragma unroll
            for (int m = 0; m < 4; ++m) { float d = cur[k][m] - cur[k + 1][m]; acc += d * d; }

        // s = (dk,0,1)
        float eo[8];
#pragma unroll
        for (int k = 0; k < 8; ++k) eo[k] = __shfl_down(cur[k][0], 1);  // j0+4 from next lane
#pragma unroll
        for (int k = 0; k < 8; ++k)
#pragma unroll
            for (int dk = -1; dk <= 1; ++dk) {
                const int kk = k + dk;
                if (kk < 0 || kk > 7) continue;
#pragma unroll
                for (int m = 0; m < 3; ++m) { float d = cur[k][m] - cur[kk][m + 1]; acc += d * d; }
                if (has_right) { float d = cur[k][3] - eo[kk]; acc += d * d; }
            }

        // ---- cross-row terms (cur, nxt): s = (dk,1,dj) ----
        if (hn) {
            float nr[8], nl[8];
#pragma unroll
            for (int k = 0; k < 8; ++k) {
                nr[k] = __shfl_down(nxt[k][0], 1);  // row i+1, j0+4
                nl[k] = __shfl_up(nxt[k][3], 1);    // row i+1, j0-1
            }
#pragma unroll
            for (int k = 0; k < 8; ++k)
#pragma unroll
                for (int dk = -1; dk <= 1; ++dk) {
                    const int kk = k + dk;
                    if (kk < 0 || kk > 7) continue;
#pragma unroll
                    for (int m = 0; m < 4; ++m) { float d = cur[k][m] - nxt[kk][m]; acc += d * d; }
#pragma unroll
                    for (int m = 0; m < 3; ++m) { float d = cur[k][m] - nxt[kk][m + 1]; acc += d * d; }
                    if (has_right) { float d = cur[k][3] - nr[kk]; acc += d * d; }
#pragma unroll
                    for (int m = 1; m < 4; ++m) { float d = cur[k][m] - nxt[kk][m - 1]; acc += d * d; }
                    if (has_left) { float d = cur[k][0] - nl[kk]; acc += d * d; }
                }
            // roll
#pragma unroll
            for (int k = 0; k < 8; ++k)
#pragma unroll
                for (int m = 0; m < 4; ++m) cur[k][m] = nxt[k][m];
        }
    }

    // Wave reduce, cross-wave via LDS, one partial per block (no atomics).
#pragma unroll
    for (int off = 32; off > 0; off >>= 1) acc += __shfl_down(acc, off);

    __shared__ float wsum[4];
    if (lane == 0) wsum[wid] = acc;
    __syncthreads();
    if (tid == 0) partial[blockIdx.x] = wsum[0] + wsum[1] + wsum[2] + wsum[3];
}

__global__ __launch_bounds__(256) void lap3d_reduce(const float* __restrict__ partial,
                                                    float* __restrict__ out) {
    float s = 0.f;
    for (int i = threadIdx.x; i < NBLOCK; i += 256) s += partial[i];
#pragma unroll
    for (int off = 32; off > 0; off >>= 1) s += __shfl_down(s, off);
    __shared__ float w[4];
    if ((threadIdx.x & 63) == 0) w[threadIdx.x >> 6] = s;
    __syncthreads();
    if (threadIdx.x == 0) out[0] = 2.0f * (w[0] + w[1] + w[2] + w[3]); // x2: forward shifts
}

extern "C" void kernel_launch(void* const* d_in, const int* in_sizes, int n_in,
                              void* d_out, int out_size, void* d_ws, size_t ws_size,
                              hipStream_t stream) {
    const float* f = (const float*)d_in[0];
    float* partial = (float*)d_ws;            // 1536 floats, well under ws_size
    float* out = (float*)d_out;
    lap3d<<<dim3(NBLOCK), dim3(256), 0, stream>>>(f, partial);
    lap3d_reduce<<<dim3(1), dim3(256), 0, stream>>>(partial, out);
}

// Round 5
// 290.571 us; speedup vs baseline: 1.2810x; 1.2810x over previous
//
#include <hip/hip_runtime.h>

// LaplacianRegularizer3D: 2 * sum over 13 forward shifts
//   S13 = {(1,0,0)} u {(dk,0,1)} u {(dk,1,dj)},  dk,dj in {-1,0,1}
// over x = f.reshape(8,12,8,256,256).
// Register-marching strips: one wave owns 4 consecutive rows of one (b,c)
// image, all 8 k-planes in registers (wave = full 256-wide row as 64xfloat4).
// Per step: load row i+1 (8 float4), within-row terms on row i, cross terms
// (i,i+1), roll. Traffic = 5/4 * 201 MB ~= 251 MB.
// R4 spill fix: edge shuffles are per-plane scalars (no [8] arrays), s-loop
// NOT unrolled (stops cross-step load hoisting that blew the 128-VGPR cap).

constexpr int WIDTH  = 256;
constexpr int HWs    = 256 * 256;
constexpr int NSTRIP = 8 * 12 * 256 / 4;   // 6144 strips
constexpr int NBLOCK = NSTRIP / 4;         // 1536 blocks (4 waves each)

__global__ __launch_bounds__(256, 4) void lap3d(const float* __restrict__ f,
                                                float* __restrict__ partial) {
    const int tid  = threadIdx.x;
    const int lane = tid & 63;
    const int wid  = tid >> 6;
    const int ss   = blockIdx.x * 4 + wid;   // strip id
    const int bc   = ss >> 6;                // 0..95
    const int i0   = (ss & 63) << 2;         // 0,4,...,252
    const float* base = f + (size_t)bc * 8 * HWs + (size_t)i0 * WIDTH + (size_t)lane * 4;

    const bool has_right  = (lane < 63);
    const bool has_left   = (lane > 0);
    const bool last_strip = (i0 == 252);     // wave-uniform

    float cur[8][4];
#pragma unroll
    for (int k = 0; k < 8; ++k) {
        float4 v = *reinterpret_cast<const float4*>(base + k * HWs);
        cur[k][0] = v.x; cur[k][1] = v.y; cur[k][2] = v.z; cur[k][3] = v.w;
    }

    float acc = 0.f;

#pragma unroll 1
    for (int s = 0; s < 4; ++s) {
        const bool hn = (s < 3) || !last_strip;   // wave-uniform

        // Issue next-row loads first (overlaps with within-row compute).
        float4 nx[8];
        if (hn) {
            const float* nb = base + (s + 1) * WIDTH;
#pragma unroll
            for (int k = 0; k < 8; ++k)
                nx[k] = *reinterpret_cast<const float4*>(nb + k * HWs);
        }

        // ---- within-row: s = (1,0,0) ----
#pragma unroll
        for (int k = 0; k < 7; ++k)
#pragma unroll
            for (int m = 0; m < 4; ++m) { float d = cur[k][m] - cur[k + 1][m]; acc += d * d; }

        // ---- within-row: s = (dk,0,1), looped by partner plane kk ----
#pragma unroll
        for (int kk = 0; kk < 8; ++kk) {
            const float e = __shfl_down(cur[kk][0], 1);  // plane kk, j0+4
#pragma unroll
            for (int k = kk - 1; k <= kk + 1; ++k) {
                if (k < 0 || k > 7) continue;
#pragma unroll
                for (int m = 0; m < 3; ++m) { float d = cur[k][m] - cur[kk][m + 1]; acc += d * d; }
                if (has_right) { float d = cur[k][3] - e; acc += d * d; }
            }
        }

        // ---- cross-row: s = (dk,1,dj), looped by partner plane kk ----
        if (hn) {
#pragma unroll
            for (int kk = 0; kk < 8; ++kk) {
                const float nr = __shfl_down(nx[kk].x, 1);  // row i+1, j0+4
                const float nl = __shfl_up(nx[kk].w, 1);    // row i+1, j0-1
                const float n0 = nx[kk].x, n1 = nx[kk].y, n2 = nx[kk].z, n3 = nx[kk].w;
#pragma unroll
                for (int k = kk - 1; k <= kk + 1; ++k) {
                    if (k < 0 || k > 7) continue;
                    // dj = 0
                    { float d = cur[k][0] - n0; acc += d * d; }
                    { float d = cur[k][1] - n1; acc += d * d; }
                    { float d = cur[k][2] - n2; acc += d * d; }
                    { float d = cur[k][3] - n3; acc += d * d; }
                    // dj = +1
                    { float d = cur[k][0] - n1; acc += d * d; }
                    { float d = cur[k][1] - n2; acc += d * d; }
                    { float d = cur[k][2] - n3; acc += d * d; }
                    if (has_right) { float d = cur[k][3] - nr; acc += d * d; }
                    // dj = -1
                    { float d = cur[k][1] - n0; acc += d * d; }
                    { float d = cur[k][2] - n1; acc += d * d; }
                    { float d = cur[k][3] - n2; acc += d * d; }
                    if (has_left) { float d = cur[k][0] - nl; acc += d * d; }
                }
            }
            // roll nxt -> cur
#pragma unroll
            for (int k = 0; k < 8; ++k) {
                cur[k][0] = nx[k].x; cur[k][1] = nx[k].y;
                cur[k][2] = nx[k].z; cur[k][3] = nx[k].w;
            }
        }
    }

    // Wave reduce, cross-wave via LDS, one partial per block (no atomics).
#pragma unroll
    for (int off = 32; off > 0; off >>= 1) acc += __shfl_down(acc, off);

    __shared__ float wsum[4];
    if (lane == 0) wsum[wid] = acc;
    __syncthreads();
    if (tid == 0) partial[blockIdx.x] = wsum[0] + wsum[1] + wsum[2] + wsum[3];
}

__global__ __launch_bounds__(256) void lap3d_reduce(const float* __restrict__ partial,
                                                    float* __restrict__ out) {
    float s = 0.f;
    for (int i = threadIdx.x; i < NBLOCK; i += 256) s += partial[i];
#pragma unroll
    for (int off = 32; off > 0; off >>= 1) s += __shfl_down(s, off);
    __shared__ float w[4];
    if ((threadIdx.x & 63) == 0) w[threadIdx.x >> 6] = s;
    __syncthreads();
    if (threadIdx.x == 0) out[0] = 2.0f * (w[0] + w[1] + w[2] + w[3]); // x2: forward shifts
}

extern "C" void kernel_launch(void* const* d_in, const int* in_sizes, int n_in,
                              void* d_out, int out_size, void* d_ws, size_t ws_size,
                              hipStream_t stream) {
    const float* f = (const float*)d_in[0];
    float* partial = (float*)d_ws;            // 1536 floats, well under ws_size
    float* out = (float*)d_out;
    lap3d<<<dim3(NBLOCK), dim3(256), 0, stream>>>(f, partial);
    lap3d_reduce<<<dim3(1), dim3(256), 0, stream>>>(partial, out);
}

// Round 6
// 277.442 us; speedup vs baseline: 1.3416x; 1.0473x over previous
//
#include <hip/hip_runtime.h>

// LaplacianRegularizer3D: 2 * sum over 13 forward shifts
//   S13 = {(1,0,0)} u {(dk,0,1)} u {(dk,1,dj)},  dk,dj in {-1,0,1}
// over x = f.reshape(8,12,8,256,256).
// R=2 register-marching strips: one wave owns 2 consecutive rows of one
// (b,c) image, all 8 k-planes in registers (wave = full 256-wide row as
// 64 x float4). Per step: load row i+1 (8 float4), within-row terms on row i,
// cross terms (i,i+1), roll. Traffic = 3/2 * 201 MB ~= 302 MB.
// 12288 strips -> 3072 blocks: 2-step serial chain + 12 blocks/CU for TLP
// (R5's 4-row strips at 1536 blocks were latency-bound: 103 us vs R3's 85).
// Per-plane scalar edge shuffles + unroll 1 keep liveness ~80 VGPR (no spill
// at launch_bounds(256,4) -- R4's 310 MB scratch WRITE_SIZE is the tripwire).

constexpr int WIDTH  = 256;
constexpr int HWs    = 256 * 256;
constexpr int NSTRIP = 8 * 12 * 256 / 2;   // 12288 strips (2 rows each)
constexpr int NBLOCK = NSTRIP / 4;         // 3072 blocks (4 waves each)

__global__ __launch_bounds__(256, 4) void lap3d(const float* __restrict__ f,
                                                float* __restrict__ partial) {
    const int tid  = threadIdx.x;
    const int lane = tid & 63;
    const int wid  = tid >> 6;
    const int ss   = blockIdx.x * 4 + wid;   // strip id
    const int bc   = ss >> 7;                // 0..95 (128 strips per image)
    const int i0   = (ss & 127) << 1;        // 0,2,...,254
    const float* base = f + (size_t)bc * 8 * HWs + (size_t)i0 * WIDTH + (size_t)lane * 4;

    const bool has_right  = (lane < 63);
    const bool has_left   = (lane > 0);
    const bool last_strip = (i0 == 254);     // wave-uniform

    float cur[8][4];
#pragma unroll
    for (int k = 0; k < 8; ++k) {
        float4 v = *reinterpret_cast<const float4*>(base + k * HWs);
        cur[k][0] = v.x; cur[k][1] = v.y; cur[k][2] = v.z; cur[k][3] = v.w;
    }

    float acc = 0.f;

#pragma unroll 1
    for (int s = 0; s < 2; ++s) {
        const bool hn = (s < 1) || !last_strip;   // wave-uniform

        // Issue next-row loads first (latency overlapped by within-row compute).
        float4 nx[8];
        if (hn) {
            const float* nb = base + (s + 1) * WIDTH;
#pragma unroll
            for (int k = 0; k < 8; ++k)
                nx[k] = *reinterpret_cast<const float4*>(nb + k * HWs);
        }

        // ---- within-row: s = (1,0,0) ----
#pragma unroll
        for (int k = 0; k < 7; ++k)
#pragma unroll
            for (int m = 0; m < 4; ++m) { float d = cur[k][m] - cur[k + 1][m]; acc += d * d; }

        // ---- within-row: s = (dk,0,1), looped by partner plane kk ----
#pragma unroll
        for (int kk = 0; kk < 8; ++kk) {
            const float e = __shfl_down(cur[kk][0], 1);  // plane kk, j0+4
#pragma unroll
            for (int k = kk - 1; k <= kk + 1; ++k) {
                if (k < 0 || k > 7) continue;
#pragma unroll
                for (int m = 0; m < 3; ++m) { float d = cur[k][m] - cur[kk][m + 1]; acc += d * d; }
                if (has_right) { float d = cur[k][3] - e; acc += d * d; }
            }
        }

        // ---- cross-row: s = (dk,1,dj), looped by partner plane kk ----
        if (hn) {
#pragma unroll
            for (int kk = 0; kk < 8; ++kk) {
                const float nr = __shfl_down(nx[kk].x, 1);  // row i+1, j0+4
                const float nl = __shfl_up(nx[kk].w, 1);    // row i+1, j0-1
                const float n0 = nx[kk].x, n1 = nx[kk].y, n2 = nx[kk].z, n3 = nx[kk].w;
#pragma unroll
                for (int k = kk - 1; k <= kk + 1; ++k) {
                    if (k < 0 || k > 7) continue;
                    // dj = 0
                    { float d = cur[k][0] - n0; acc += d * d; }
                    { float d = cur[k][1] - n1; acc += d * d; }
                    { float d = cur[k][2] - n2; acc += d * d; }
                    { float d = cur[k][3] - n3; acc += d * d; }
                    // dj = +1
                    { float d = cur[k][0] - n1; acc += d * d; }
                    { float d = cur[k][1] - n2; acc += d * d; }
                    { float d = cur[k][2] - n3; acc += d * d; }
                    if (has_right) { float d = cur[k][3] - nr; acc += d * d; }
                    // dj = -1
                    { float d = cur[k][1] - n0; acc += d * d; }
                    { float d = cur[k][2] - n1; acc += d * d; }
                    { float d = cur[k][3] - n2; acc += d * d; }
                    if (has_left) { float d = cur[k][0] - nl; acc += d * d; }
                }
            }
            // roll nxt -> cur
#pragma unroll
            for (int k = 0; k < 8; ++k) {
                cur[k][0] = nx[k].x; cur[k][1] = nx[k].y;
                cur[k][2] = nx[k].z; cur[k][3] = nx[k].w;
            }
        }
    }

    // Wave reduce, cross-wave via LDS, one partial per block (no atomics).
#pragma unroll
    for (int off = 32; off > 0; off >>= 1) acc += __shfl_down(acc, off);

    __shared__ float wsum[4];
    if (lane == 0) wsum[wid] = acc;
    __syncthreads();
    if (tid == 0) partial[blockIdx.x] = wsum[0] + wsum[1] + wsum[2] + wsum[3];
}

__global__ __launch_bounds__(256) void lap3d_reduce(const float* __restrict__ partial,
                                                    float* __restrict__ out) {
    float s = 0.f;
    for (int i = threadIdx.x; i < NBLOCK; i += 256) s += partial[i];
#pragma unroll
    for (int off = 32; off > 0; off >>= 1) s += __shfl_down(s, off);
    __shared__ float w[4];
    if ((threadIdx.x & 63) == 0) w[threadIdx.x >> 6] = s;
    __syncthreads();
    if (threadIdx.x == 0) out[0] = 2.0f * (w[0] + w[1] + w[2] + w[3]); // x2: forward shifts
}

extern "C" void kernel_launch(void* const* d_in, const int* in_sizes, int n_in,
                              void* d_out, int out_size, void* d_ws, size_t ws_size,
                              hipStream_t stream) {
    const float* f = (const float*)d_in[0];
    float* partial = (float*)d_ws;            // 3072 floats, well under ws_size
    float* out = (float*)d_out;
    lap3d<<<dim3(NBLOCK), dim3(256), 0, stream>>>(f, partial);
    lap3d_reduce<<<dim3(1), dim3(256), 0, stream>>>(partial, out);
}